// Round 5
// baseline (505.800 us; speedup 1.0000x reference)
//
#include <hip/hip_runtime.h>
#include <math.h>

#define BB 16
#define CC 64
#define HH 256
#define WW 256
#define HWSZ (HH * WW)
#define NP (BB * CC)        // 1024 planes
#define GROUPS 4            // pipeline groups; group = 4 batches = 67 MB of x
#define BPG (BB / GROUPS)   // 4 batches per group
#define PPG (BPG * CC)      // 256 planes per group
#define QROWS (HH / 4)      // 64 rows per quarter-plane mean block
#define STRIPS 4            // conv strips per plane; wave owns 16 rows
#define RPW (HH / (STRIPS * 4))

typedef float f4 __attribute__((ext_vector_type(4)));

// ---------------- mean (quarter-plane partials, per group) ----------------
// grid = PPG*4 blocks: block = (plane_local<<2)|quarter. Each block sums a
// 64-row quarter of its plane and writes the raw partial sum to
// avg4g[plane_local*4 + quarter]. No atomics, no zeroing needed.
__global__ __launch_bounds__(256) void mean_kernel(const float* __restrict__ xg,
                                                   float* __restrict__ avg4g) {
    const int pl = blockIdx.x >> 2;
    const int q  = blockIdx.x & 3;
    const f4* xv = (const f4*)(xg + (size_t)pl * HWSZ + (size_t)q * QROWS * WW);
    float s0 = 0.f, s1 = 0.f, s2 = 0.f, s3 = 0.f;
    for (int i = threadIdx.x; i < 1024; i += 256) {   // quarter = 4096 f4
        f4 a = xv[i];
        f4 b = xv[i + 1024];
        f4 c = xv[i + 2048];
        f4 d = xv[i + 3072];
        s0 += a.x + a.y + a.z + a.w;
        s1 += b.x + b.y + b.z + b.w;
        s2 += c.x + c.y + c.z + c.w;
        s3 += d.x + d.y + d.z + d.w;
    }
    float s = (s0 + s1) + (s2 + s3);
    for (int off = 32; off > 0; off >>= 1) s += __shfl_down(s, off, 64);
    __shared__ float ws[4];
    int lane = threadIdx.x & 63, wid = threadIdx.x >> 6;
    if (lane == 0) ws[wid] = s;
    __syncthreads();
    if (threadIdx.x == 0) {
        avg4g[pl * 4 + q] = ws[0] + ws[1] + ws[2] + ws[3];   // raw sum
    }
}

// ---------------- conv (per group): depthwise 3x3 + fused taps + epilogue ----
// Identical math to the verified R2 kernel; group-local pointers. The group's
// x (67 MB) was just streamed by mean_g -> guaranteed Infinity-Cache resident
// (67 read + 67 written = 134 MB << 256 MB), so the re-read is L3-served.
// Depth-2 row pipeline, shuffle halos, nontemporal out stores.
__global__ __launch_bounds__(256, 4) void conv_kernel(const float* __restrict__ xg,
                                                      const float* __restrict__ avg4g,
                                                      const float* __restrict__ w1,
                                                      const float* __restrict__ b1,
                                                      const float* __restrict__ fscale,
                                                      const float* __restrict__ conv_bias,
                                                      float* __restrict__ outg) {
    const int pl    = blockIdx.x >> 2;          // plane within group (0..255)
    const int strip = blockIdx.x & (STRIPS - 1);
    const int wave  = threadIdx.x >> 6;
    const int lane  = threadIdx.x & 63;
    const int c  = pl & (CC - 1);               // channel (global)
    const int bl = pl >> 6;                     // batch within group (0..3)
    const int h0 = strip * (HH / STRIPS) + wave * RPW;
    const float* xp = xg + (size_t)pl * HWSZ;
    float* op = outg + (size_t)pl * HWSZ;

    // fused dynamic taps: dyn = b1 + avg[b,:] . w1[c*9+j,:], sigmoid
    __shared__ float kk[12];
    if (threadIdx.x < 9) {
        const float* a4   = avg4g + (size_t)bl * CC * 4;
        const float* wrow = w1 + (size_t)(c * 9 + threadIdx.x) * CC;
        float s = b1[c * 9 + threadIdx.x];
#pragma unroll
        for (int c2 = 0; c2 < CC; ++c2) {
            float av = (a4[c2 * 4 + 0] + a4[c2 * 4 + 1] +
                        a4[c2 * 4 + 2] + a4[c2 * 4 + 3]) * (1.0f / (float)HWSZ);
            s += av * wrow[c2];
        }
        kk[threadIdx.x] = 1.0f / (1.0f + expf(-s));
    }
    __syncthreads();
    const float k0 = kk[0], k1 = kk[1], k2 = kk[2];
    const float k3 = kk[3], k4 = kk[4], k5 = kk[5];
    const float k6 = kk[6], k7 = kk[7], k8 = kk[8];
    const float fs = fscale[c];
    const float cb = conv_bias[c];

    auto ldrow = [&](int r) -> f4 {
        if ((unsigned)r < (unsigned)HH) return ((const f4*)(xp + r * WW))[lane];
        return (f4){0.f, 0.f, 0.f, 0.f};
    };
    auto hL = [&](f4 v) { float t = __shfl_up(v.w, 1, 64); return lane == 0 ? 0.f : t; };
    auto hR = [&](f4 v) { float t = __shfl_down(v.x, 1, 64); return lane == 63 ? 0.f : t; };

    // register window: rows h-1, h, h+1, h+2 (rA..rD) + 2 prefetched (rE,rF)
    f4 rA = ldrow(h0 - 1);
    f4 rB = ldrow(h0);
    f4 rC = ldrow(h0 + 1);
    f4 rD = ldrow(h0 + 2);
    float lA = hL(rA), RA = hR(rA);
    float lB = hL(rB), RB = hR(rB);
    float lC = hL(rC), RC = hR(rC);
    float lD = hL(rD), RD = hR(rD);

    for (int h = h0; h < h0 + RPW; h += 2) {
        f4 rE = ldrow(h + 3);   // in flight during compute
        f4 rF = ldrow(h + 4);   // in flight during compute

        // row h: sources rA (h-1), rB (h), rC (h+1)
        f4 y0;
        y0.x = cb + k0 * lA   + k1 * rA.x + k2 * rA.y
                  + k3 * lB   + k4 * rB.x + k5 * rB.y
                  + k6 * lC   + k7 * rC.x + k8 * rC.y;
        y0.y = cb + k0 * rA.x + k1 * rA.y + k2 * rA.z
                  + k3 * rB.x + k4 * rB.y + k5 * rB.z
                  + k6 * rC.x + k7 * rC.y + k8 * rC.z;
        y0.z = cb + k0 * rA.y + k1 * rA.z + k2 * rA.w
                  + k3 * rB.y + k4 * rB.z + k5 * rB.w
                  + k6 * rC.y + k7 * rC.z + k8 * rC.w;
        y0.w = cb + k0 * rA.z + k1 * rA.w + k2 * RA
                  + k3 * rB.z + k4 * rB.w + k5 * RB
                  + k6 * rC.z + k7 * rC.w + k8 * RC;
        f4 o0;
        o0.x = (rB.x - y0.x) * fs * rB.x + y0.x;
        o0.y = (rB.y - y0.y) * fs * rB.y + y0.y;
        o0.z = (rB.z - y0.z) * fs * rB.z + y0.z;
        o0.w = (rB.w - y0.w) * fs * rB.w + y0.w;
        __builtin_nontemporal_store(o0, (f4*)(op + h * WW) + lane);

        // row h+1: sources rB (h), rC (h+1), rD (h+2)
        f4 y1;
        y1.x = cb + k0 * lB   + k1 * rB.x + k2 * rB.y
                  + k3 * lC   + k4 * rC.x + k5 * rC.y
                  + k6 * lD   + k7 * rD.x + k8 * rD.y;
        y1.y = cb + k0 * rB.x + k1 * rB.y + k2 * rB.z
                  + k3 * rC.x + k4 * rC.y + k5 * rC.z
                  + k6 * rD.x + k7 * rD.y + k8 * rD.z;
        y1.z = cb + k0 * rB.y + k1 * rB.z + k2 * rB.w
                  + k3 * rC.y + k4 * rC.z + k5 * rC.w
                  + k6 * rD.y + k7 * rD.z + k8 * rD.w;
        y1.w = cb + k0 * rB.z + k1 * rB.w + k2 * RB
                  + k3 * rC.z + k4 * rC.w + k5 * RC
                  + k6 * rD.z + k7 * rD.w + k8 * RD;
        f4 o1;
        o1.x = (rC.x - y1.x) * fs * rC.x + y1.x;
        o1.y = (rC.y - y1.y) * fs * rC.y + y1.y;
        o1.z = (rC.z - y1.z) * fs * rC.z + y1.z;
        o1.w = (rC.w - y1.w) * fs * rC.w + y1.w;
        __builtin_nontemporal_store(o1, (f4*)(op + (h + 1) * WW) + lane);

        // halos for the prefetched rows (after compute: loads have landed)
        float lE = hL(rE), RE = hR(rE);
        float lF = hL(rF), RF = hR(rF);

        // shift window by 2
        rA = rC; lA = lC; RA = RC;
        rB = rD; lB = lD; RB = RD;
        rC = rE; lC = lE; RC = RE;
        rD = rF; lD = lF; RD = RF;
    }
}

extern "C" void kernel_launch(void* const* d_in, const int* in_sizes, int n_in,
                              void* d_out, int out_size, void* d_ws, size_t ws_size,
                              hipStream_t stream) {
    const float* x         = (const float*)d_in[0];
    const float* w1        = (const float*)d_in[1];
    const float* b1        = (const float*)d_in[2];
    const float* fscale    = (const float*)d_in[3];
    const float* conv_bias = (const float*)d_in[4];
    float* out = (float*)d_out;
    float* avg4 = (float*)d_ws;       // NP*4 floats of raw partial sums

    for (int g = 0; g < GROUPS; ++g) {
        const float* xg     = x    + (size_t)g * PPG * HWSZ;
        float*       outg   = out  + (size_t)g * PPG * HWSZ;
        float*       avg4g  = avg4 + (size_t)g * PPG * 4;
        mean_kernel<<<PPG * 4, 256, 0, stream>>>(xg, avg4g);
        conv_kernel<<<PPG * STRIPS, 256, 0, stream>>>(xg, avg4g, w1, b1,
                                                      fscale, conv_bias, outg);
    }
}